// Round 2
// baseline (12615.445 us; speedup 1.0000x reference)
//
#include <hip/hip_runtime.h>

#define D_  1280
#define T_  2048
#define B_  16
#define NW  40     // scan workgroups
#define RPW 32     // W_h rows per scan workgroup
#define KS  320    // K-slice per wave in scan

typedef unsigned short u16;
typedef unsigned int   u32;
typedef __attribute__((ext_vector_type(8))) short bf16x8;   // 8 bf16 = 4 VGPRs
typedef __attribute__((ext_vector_type(4))) float f32x4;
typedef __attribute__((ext_vector_type(4))) int   i32x4;

__device__ __forceinline__ float bf2f(u16 u) {
  union { u32 i; float f; } v; v.i = ((u32)u) << 16; return v.f;
}
__device__ __forceinline__ u16 f2bf(float f) {
  union { float f; u32 i; } v; v.f = f;
  u32 r = v.i + 0x7fffu + ((v.i >> 16) & 1u);   // RNE
  return (u16)(r >> 16);
}
__device__ __forceinline__ float sigm(float x) { return 1.f / (1.f + __expf(-x)); }
__device__ __forceinline__ float tanh_(float x) { return 1.f - 2.f / (__expf(2.f * x) + 1.f); }

// ---------------------------------------------------------------------------
// dtype detection: bf16 halfwords of N(0,1)-scale data have exponent field in
// ~[100,140] nearly always; fp32 data read as u16 has random low-halfwords
// (~16% in range) -> count over 256 samples separates at >5 sigma.
// ---------------------------------------------------------------------------
__global__ void detect_k(const u16* __restrict__ x, int* __restrict__ dflag) {
  __shared__ int cnt;
  if (threadIdx.x == 0) cnt = 0;
  __syncthreads();
  u16 u = x[threadIdx.x];
  int e = (u >> 7) & 0xFF;
  if (e >= 100 && e <= 140) atomicAdd(&cnt, 1);
  __syncthreads();
  if (threadIdx.x == 0) *dflag = (cnt < 192) ? 1 : 0;   // 1 = fp32 inputs
}

// convert (or copy) n elements to bf16; n arbitrary, 8 elems/thread
__global__ void cvt_k(const void* __restrict__ src, u16* __restrict__ dst,
                      long n, const int* __restrict__ dflag) {
  const int fp32 = *dflag;
  long base = ((long)blockIdx.x * 256 + threadIdx.x) * 8;
  if (base + 8 <= n) {
    if (fp32) {
      const float* s = (const float*)src;
      f32x4 f0 = *(const f32x4*)(s + base);
      f32x4 f1 = *(const f32x4*)(s + base + 4);
      u32 w0 = (u32)f2bf(f0[0]) | ((u32)f2bf(f0[1]) << 16);
      u32 w1 = (u32)f2bf(f0[2]) | ((u32)f2bf(f0[3]) << 16);
      u32 w2 = (u32)f2bf(f1[0]) | ((u32)f2bf(f1[1]) << 16);
      u32 w3 = (u32)f2bf(f1[2]) | ((u32)f2bf(f1[3]) << 16);
      i32x4 o = { (int)w0, (int)w1, (int)w2, (int)w3 };
      *(i32x4*)(dst + base) = o;
    } else {
      *(i32x4*)(dst + base) = *(const i32x4*)((const u16*)src + base);
    }
  } else {
    for (long i = base; i < n; ++i)
      dst[i] = fp32 ? f2bf(((const float*)src)[i]) : ((const u16*)src)[i];
  }
}

// ---------------------------------------------------------------------------
// GEMM: C(M x N) = A(M x K=1280) * B^T, B given as (N x K) row-major bf16.
// 128x128 tile, BK=32, 256 threads = 4 waves in 2x2 grid, 64x64 per wave.
// EPI 0: N=2560, silu both halves; n<1280 -> C0[m,n] (b,t,d); n>=1280 -> C1 (t,b,d)
// EPI 1: N=1280, +bias -> C0 in (t,b,d)
// EPI 2: N=1280, rows are (t*16+b) -> Cout (b,t,d), dtype per dflag
// ---------------------------------------------------------------------------
template<int EPI>
__global__ __launch_bounds__(256, 2) void gemm_bt(
    const u16* __restrict__ A, const u16* __restrict__ B,
    u16* __restrict__ C0, u16* __restrict__ C1,
    const u16* __restrict__ bias,
    void* __restrict__ Cout, const int* __restrict__ dflag)
{
  __shared__ __align__(16) u16 As[128 * 40];
  __shared__ __align__(16) u16 Bs[128 * 40];

  const int fp32o = (EPI == 2) ? *dflag : 0;
  const int tid  = threadIdx.x;
  const int lane = tid & 63;
  const int qq   = lane >> 4, ln = lane & 15;
  const int wave = tid >> 6;
  const int wm   = (wave >> 1) * 64, wn = (wave & 1) * 64;
  const long m0  = (long)blockIdx.y * 128;
  const long n0  = (long)blockIdx.x * 128;

  const int r0 = tid >> 2, c0 = (tid & 3) * 8;
  const int r1 = r0 + 64;

  f32x4 acc[4][4];
  #pragma unroll
  for (int i = 0; i < 4; ++i)
    #pragma unroll
    for (int j = 0; j < 4; ++j) acc[i][j] = (f32x4){0.f, 0.f, 0.f, 0.f};

  for (int kt = 0; kt < D_; kt += 32) {
    i32x4 av0 = *(const i32x4*)(A + (m0 + r0) * D_ + kt + c0);
    i32x4 av1 = *(const i32x4*)(A + (m0 + r1) * D_ + kt + c0);
    i32x4 bv0 = *(const i32x4*)(B + (n0 + r0) * D_ + kt + c0);
    i32x4 bv1 = *(const i32x4*)(B + (n0 + r1) * D_ + kt + c0);
    __syncthreads();                       // previous iter's ds_reads done
    *(i32x4*)(As + r0 * 40 + c0) = av0;
    *(i32x4*)(As + r1 * 40 + c0) = av1;
    *(i32x4*)(Bs + r0 * 40 + c0) = bv0;
    *(i32x4*)(Bs + r1 * 40 + c0) = bv1;
    __syncthreads();

    bf16x8 af[4], bfr[4];
    #pragma unroll
    for (int i = 0; i < 4; ++i)
      af[i] = *(const bf16x8*)(As + (wm + i * 16 + ln) * 40 + qq * 8);
    #pragma unroll
    for (int j = 0; j < 4; ++j)
      bfr[j] = *(const bf16x8*)(Bs + (wn + j * 16 + ln) * 40 + qq * 8);
    #pragma unroll
    for (int i = 0; i < 4; ++i)
      #pragma unroll
      for (int j = 0; j < 4; ++j)
        acc[i][j] = __builtin_amdgcn_mfma_f32_16x16x32_bf16(af[i], bfr[j], acc[i][j], 0, 0, 0);
  }

  #pragma unroll
  for (int i = 0; i < 4; ++i)
    #pragma unroll
    for (int j = 0; j < 4; ++j)
      #pragma unroll
      for (int r = 0; r < 4; ++r) {
        long m = m0 + wm + i * 16 + qq * 4 + r;       // C/D: row = quad*4+reg
        long n = n0 + wn + j * 16 + ln;               //      col = lane&15
        float v = acc[i][j][r];
        if (EPI == 0) {
          float s = v * sigm(v);                      // silu
          long t = m & 2047, bb = m >> 11;
          if (n < D_) C0[m * D_ + n] = f2bf(s);                       // x_proj (b,t,d)
          else        C1[(t * 16 + bb) * D_ + (n - D_)] = f2bf(s);    // silu(z) (t,b,d)
        } else if (EPI == 1) {
          long t = m & 2047, bb = m >> 11;
          C0[(t * 16 + bb) * D_ + n] = f2bf(v + bf2f(bias[n]));       // x_pre (t,b,d)
        } else {
          long bb = m & 15, t = m >> 4;
          long idx = (bb * 2048 + t) * D_ + n;                        // out (b,t,d)
          if (fp32o) ((float*)Cout)[idx] = v;
          else       ((u16*)Cout)[idx]   = f2bf(v);
        }
      }
}

// ---------------------------------------------------------------------------
// Sequential scan: h_t = tanh(x_pre_t + h_{t-1} @ W_h^T); out_t = h_t * silu(z_t)
// 40 WGs x 256 thr. WG owns 32 rows of W_h in registers (MFMA A-frags); wave w
// owns K in [w*320,(w+1)*320). Cross-wave K-reduce via LDS. Device flag barrier.
// sout aliases xpre (read-before-write at same address by same thread).
// ---------------------------------------------------------------------------
__global__ __launch_bounds__(256, 1) void scan_rnn(
    const u16* __restrict__ Wh, const u16* __restrict__ xpre,
    const u16* __restrict__ zs, u16* __restrict__ sout,
    u16* __restrict__ hbuf, int* __restrict__ flags,
    void* __restrict__ dout, const int* __restrict__ dflag)
{
  const int fp32o = *dflag;
  const int wg   = blockIdx.x;
  const int tid  = threadIdx.x;
  const int lane = tid & 63;
  const int wave = tid >> 6;
  const int qq   = lane >> 4, ln = lane & 15;

  // persistent W_h fragments: A[m=lane&15][k=quad*8+j], rows wg*32 + i*16 + ln
  bf16x8 wfrag[2][10];
  #pragma unroll
  for (int i = 0; i < 2; ++i) {
    const u16* wrow = Wh + (long)(wg * RPW + i * 16 + ln) * D_ + wave * KS;
    #pragma unroll
    for (int c = 0; c < 10; ++c)
      wfrag[i][c] = *(const bf16x8*)(wrow + c * 32 + qq * 8);
  }

  __shared__ float red[4 * 2 * 16 * 16];   // [wave][tile][row][col] fp32 partials

  const int batch = tid >> 4;
  const int dl0   = (tid & 15) * 2;
  const int d0    = wg * RPW + dl0;
  const int tile  = dl0 >> 4;
  const int row0  = dl0 & 15;

  for (int t = 0; t < T_; ++t) {
    const u16* hc = hbuf + (t & 1) * (B_ * D_);
    u16*       hn = hbuf + ((t + 1) & 1) * (B_ * D_);

    const long pidx = (long)(t * B_ + batch) * D_ + d0;
    u32 xp2 = *(const u32*)(xpre + pidx);   // read BEFORE in-place store below
    u32 zs2 = *(const u32*)(zs + pidx);

    f32x4 a0 = (f32x4){0.f,0.f,0.f,0.f}, a1 = (f32x4){0.f,0.f,0.f,0.f};
    const u16* hrow = hc + (long)ln * D_ + wave * KS;   // B[n=batch=lane&15][k]
    #pragma unroll
    for (int c = 0; c < 10; ++c) {
      bf16x8 hf = *(const bf16x8*)(hrow + c * 32 + qq * 8);
      a0 = __builtin_amdgcn_mfma_f32_16x16x32_bf16(wfrag[0][c], hf, a0, 0, 0, 0);
      a1 = __builtin_amdgcn_mfma_f32_16x16x32_bf16(wfrag[1][c], hf, a1, 0, 0, 0);
    }
    #pragma unroll
    for (int r = 0; r < 4; ++r) {
      red[((wave * 2 + 0) * 16 + qq * 4 + r) * 16 + ln] = a0[r];
      red[((wave * 2 + 1) * 16 + qq * 4 + r) * 16 + ln] = a1[r];
    }
    __syncthreads();

    float s0 = red[((0 + tile) * 16 + row0) * 16 + batch]
             + red[((2 + tile) * 16 + row0) * 16 + batch]
             + red[((4 + tile) * 16 + row0) * 16 + batch]
             + red[((6 + tile) * 16 + row0) * 16 + batch];
    float s1 = red[((0 + tile) * 16 + row0 + 1) * 16 + batch]
             + red[((2 + tile) * 16 + row0 + 1) * 16 + batch]
             + red[((4 + tile) * 16 + row0 + 1) * 16 + batch]
             + red[((6 + tile) * 16 + row0 + 1) * 16 + batch];

    float h0 = tanh_(bf2f((u16)(xp2 & 0xffff)) + s0);
    float h1 = tanh_(bf2f((u16)(xp2 >> 16)) + s1);
    float o0 = h0 * bf2f((u16)(zs2 & 0xffff));   // zs already silu'd
    float o1 = h1 * bf2f((u16)(zs2 >> 16));

    *(u32*)(sout + pidx) = (u32)f2bf(o0) | ((u32)f2bf(o1) << 16);
    u32 hpack = (u32)f2bf(h0) | ((u32)f2bf(h1) << 16);
    *(u32*)(hn + batch * D_ + d0) = hpack;

    if (t == T_ - 1) {                           // h_final, dtype-branched
      if (fp32o) {
        float* hf32 = (float*)dout + (long)B_ * T_ * D_;
        hf32[batch * D_ + d0]     = h0;
        hf32[batch * D_ + d0 + 1] = h1;
      } else {
        u16* hb = (u16*)dout + (long)B_ * T_ * D_;
        *(u32*)(hb + batch * D_ + d0) = hpack;
      }
      break;                                     // uniform exit
    }

    __syncthreads();                             // drains vmcnt: all stores done
    if (tid == 0) {
      __threadfence();                           // release (agent: wb L2)
      atomicAdd(&flags[t], 1);
      while (__hip_atomic_load(&flags[t], __ATOMIC_ACQUIRE, __HIP_MEMORY_SCOPE_AGENT) < NW) {
        __builtin_amdgcn_s_sleep(1);
      }
      __threadfence();                           // acquire (agent: inv L1/L2)
    }
    __syncthreads();
  }
}

// ---------------------------------------------------------------------------
extern "C" void kernel_launch(void* const* d_in, const int* in_sizes, int n_in,
                              void* d_out, int out_size, void* d_ws, size_t ws_size,
                              hipStream_t stream) {
  const void* x     = d_in[0];   // (16,2048,1280)
  const void* W_in  = d_in[1];   // (2560,1280)
  const void* W_out = d_in[2];   // (1280,1280)
  const void* W_x   = d_in[3];   // (1280,1280)
  const void* W_h   = d_in[4];   // (1280,1280)
  const void* bias  = d_in[5];   // (1280,)

  const size_t SZ = (size_t)32768 * D_ * sizeof(u16);  // 83,886,080 B
  char* ws = (char*)d_ws;
  u16* bufA  = (u16*)(ws);                        // x_bf16 -> xpre -> sout (in place)
  u16* bufB  = (u16*)(ws + SZ);                   // x_proj
  u16* wi    = (u16*)(ws + 2 * SZ);               // W_in  bf16 (6,553,600 B)
  u16* wo    = (u16*)(ws + 2 * SZ +  6553600);    // W_out bf16 (3,276,800 B)
  u16* wx    = (u16*)(ws + 2 * SZ +  9830400);    // W_x   bf16
  u16* wh    = (u16*)(ws + 2 * SZ + 13107200);    // W_h   bf16
  u16* bb_   = (u16*)(ws + 2 * SZ + 16384000);    // bias  bf16 (2,560 B)
  u16* hbuf  = (u16*)(ws + 2 * SZ + 16386560);    // 2 x (16 x 1280) bf16 ring
  int* flags = (int*)(ws + 2 * SZ + 16386560 + 81920);
  int* dflag = (int*)(ws + 2 * SZ + 16386560 + 81920 + 8192);
  u16* zsil  = (u16*)d_out;                       // silu(z) parks in d_out; dead
                                                  // before gemm<2> overwrites it

  hipMemsetAsync(hbuf, 0, 81920 + 8192, stream);

  detect_k<<<1, 256, 0, stream>>>((const u16*)x, dflag);
  cvt_k<<<20480, 256, 0, stream>>>(x,     bufA, 41943040L, dflag);
  cvt_k<<< 1600, 256, 0, stream>>>(W_in,  wi,    3276800L, dflag);
  cvt_k<<<  800, 256, 0, stream>>>(W_out, wo,    1638400L, dflag);
  cvt_k<<<  800, 256, 0, stream>>>(W_x,   wx,    1638400L, dflag);
  cvt_k<<<  800, 256, 0, stream>>>(W_h,   wh,    1638400L, dflag);
  cvt_k<<<    1, 256, 0, stream>>>(bias,  bb_,      1280L, dflag);

  gemm_bt<0><<<dim3(20, 256), 256, 0, stream>>>(bufA, wi, bufB, zsil, nullptr, nullptr, dflag);
  gemm_bt<1><<<dim3(10, 256), 256, 0, stream>>>(bufB, wx, bufA, nullptr, bb_, nullptr, dflag);
  scan_rnn<<<NW, 256, 0, stream>>>(wh, bufA, zsil, bufA, hbuf, flags, d_out, dflag);
  gemm_bt<2><<<dim3(10, 256), 256, 0, stream>>>(bufA, wo, nullptr, nullptr, nullptr, d_out, dflag);
}

// Round 3
// 11551.445 us; speedup vs baseline: 1.0921x; 1.0921x over previous
//
#include <hip/hip_runtime.h>

#define D_  1280
#define T_  2048
#define B_  16
#define NW  40     // scan workgroups
#define RPW 32     // W_h rows per scan workgroup
#define KS  320    // K-slice per wave in scan

typedef unsigned short u16;
typedef unsigned int   u32;
typedef unsigned long long u64;
typedef __attribute__((ext_vector_type(8))) short bf16x8;   // 8 bf16 = 4 VGPRs
typedef __attribute__((ext_vector_type(4))) float f32x4;
typedef __attribute__((ext_vector_type(4))) int   i32x4;

__device__ __forceinline__ float bf2f(u16 u) {
  union { u32 i; float f; } v; v.i = ((u32)u) << 16; return v.f;
}
__device__ __forceinline__ u16 f2bf(float f) {
  union { float f; u32 i; } v; v.f = f;
  u32 r = v.i + 0x7fffu + ((v.i >> 16) & 1u);   // RNE
  return (u16)(r >> 16);
}
__device__ __forceinline__ float sigm(float x) { return 1.f / (1.f + __expf(-x)); }
__device__ __forceinline__ float tanh_(float x) { return 1.f - 2.f / (__expf(2.f * x) + 1.f); }

// ---------------------------------------------------------------------------
// dtype detection: bf16 halfwords of N(0,1)-scale data have exponent field in
// ~[100,140] nearly always; fp32 low-halfwords are ~random -> count separates.
// ---------------------------------------------------------------------------
__global__ void detect_k(const u16* __restrict__ x, int* __restrict__ dflag) {
  __shared__ int cnt;
  if (threadIdx.x == 0) cnt = 0;
  __syncthreads();
  u16 u = x[threadIdx.x];
  int e = (u >> 7) & 0xFF;
  if (e >= 100 && e <= 140) atomicAdd(&cnt, 1);
  __syncthreads();
  if (threadIdx.x == 0) *dflag = (cnt < 192) ? 1 : 0;   // 1 = fp32 inputs
}

// convert (or copy) n elements to bf16; n arbitrary, 8 elems/thread
__global__ void cvt_k(const void* __restrict__ src, u16* __restrict__ dst,
                      long n, const int* __restrict__ dflag) {
  const int fp32 = *dflag;
  long base = ((long)blockIdx.x * 256 + threadIdx.x) * 8;
  if (base + 8 <= n) {
    if (fp32) {
      const float* s = (const float*)src;
      f32x4 f0 = *(const f32x4*)(s + base);
      f32x4 f1 = *(const f32x4*)(s + base + 4);
      u32 w0 = (u32)f2bf(f0[0]) | ((u32)f2bf(f0[1]) << 16);
      u32 w1 = (u32)f2bf(f0[2]) | ((u32)f2bf(f0[3]) << 16);
      u32 w2 = (u32)f2bf(f1[0]) | ((u32)f2bf(f1[1]) << 16);
      u32 w3 = (u32)f2bf(f1[2]) | ((u32)f2bf(f1[3]) << 16);
      i32x4 o = { (int)w0, (int)w1, (int)w2, (int)w3 };
      *(i32x4*)(dst + base) = o;
    } else {
      *(i32x4*)(dst + base) = *(const i32x4*)((const u16*)src + base);
    }
  } else {
    for (long i = base; i < n; ++i)
      dst[i] = fp32 ? f2bf(((const float*)src)[i]) : ((const u16*)src)[i];
  }
}

// ---------------------------------------------------------------------------
// GEMM: C(M x N) = A(M x K=1280) * B^T, B given as (N x K) row-major bf16.
// 128x128 tile, BK=32, 256 threads = 4 waves in 2x2 grid, 64x64 per wave.
// ---------------------------------------------------------------------------
template<int EPI>
__global__ __launch_bounds__(256, 2) void gemm_bt(
    const u16* __restrict__ A, const u16* __restrict__ B,
    u16* __restrict__ C0, u16* __restrict__ C1,
    const u16* __restrict__ bias,
    void* __restrict__ Cout, const int* __restrict__ dflag)
{
  __shared__ __align__(16) u16 As[128 * 40];
  __shared__ __align__(16) u16 Bs[128 * 40];

  const int fp32o = (EPI == 2) ? *dflag : 0;
  const int tid  = threadIdx.x;
  const int lane = tid & 63;
  const int qq   = lane >> 4, ln = lane & 15;
  const int wave = tid >> 6;
  const int wm   = (wave >> 1) * 64, wn = (wave & 1) * 64;
  const long m0  = (long)blockIdx.y * 128;
  const long n0  = (long)blockIdx.x * 128;

  const int r0 = tid >> 2, c0 = (tid & 3) * 8;
  const int r1 = r0 + 64;

  f32x4 acc[4][4];
  #pragma unroll
  for (int i = 0; i < 4; ++i)
    #pragma unroll
    for (int j = 0; j < 4; ++j) acc[i][j] = (f32x4){0.f, 0.f, 0.f, 0.f};

  for (int kt = 0; kt < D_; kt += 32) {
    i32x4 av0 = *(const i32x4*)(A + (m0 + r0) * D_ + kt + c0);
    i32x4 av1 = *(const i32x4*)(A + (m0 + r1) * D_ + kt + c0);
    i32x4 bv0 = *(const i32x4*)(B + (n0 + r0) * D_ + kt + c0);
    i32x4 bv1 = *(const i32x4*)(B + (n0 + r1) * D_ + kt + c0);
    __syncthreads();                       // previous iter's ds_reads done
    *(i32x4*)(As + r0 * 40 + c0) = av0;
    *(i32x4*)(As + r1 * 40 + c0) = av1;
    *(i32x4*)(Bs + r0 * 40 + c0) = bv0;
    *(i32x4*)(Bs + r1 * 40 + c0) = bv1;
    __syncthreads();

    bf16x8 af[4], bfr[4];
    #pragma unroll
    for (int i = 0; i < 4; ++i)
      af[i] = *(const bf16x8*)(As + (wm + i * 16 + ln) * 40 + qq * 8);
    #pragma unroll
    for (int j = 0; j < 4; ++j)
      bfr[j] = *(const bf16x8*)(Bs + (wn + j * 16 + ln) * 40 + qq * 8);
    #pragma unroll
    for (int i = 0; i < 4; ++i)
      #pragma unroll
      for (int j = 0; j < 4; ++j)
        acc[i][j] = __builtin_amdgcn_mfma_f32_16x16x32_bf16(af[i], bfr[j], acc[i][j], 0, 0, 0);
  }

  #pragma unroll
  for (int i = 0; i < 4; ++i)
    #pragma unroll
    for (int j = 0; j < 4; ++j)
      #pragma unroll
      for (int r = 0; r < 4; ++r) {
        long m = m0 + wm + i * 16 + qq * 4 + r;       // C/D: row = quad*4+reg
        long n = n0 + wn + j * 16 + ln;               //      col = lane&15
        float v = acc[i][j][r];
        if (EPI == 0) {
          float s = v * sigm(v);                      // silu
          long t = m & 2047, bb = m >> 11;
          if (n < D_) C0[m * D_ + n] = f2bf(s);                       // x_proj (b,t,d)
          else        C1[(t * 16 + bb) * D_ + (n - D_)] = f2bf(s);    // silu(z) (t,b,d)
        } else if (EPI == 1) {
          long t = m & 2047, bb = m >> 11;
          C0[(t * 16 + bb) * D_ + n] = f2bf(v + bf2f(bias[n]));       // x_pre (t,b,d)
        } else {
          long bb = m & 15, t = m >> 4;
          long idx = (bb * 2048 + t) * D_ + n;                        // out (b,t,d)
          if (fp32o) ((float*)Cout)[idx] = v;
          else       ((u16*)Cout)[idx]   = f2bf(v);
        }
      }
}

// ---------------------------------------------------------------------------
// Sequential scan, fence-free: all cross-WG data (h ring, done flags) moves via
// RELAXED agent-scope atomics that bypass L1/L2 and meet at the LIC (coherence
// point). Release ordering = __syncthreads' vmcnt(0) drain before s_barrier.
// Per-WG flag stores (no RMW serialization); every wave polls all 40 flags
// with one coalesced load + __all, releasing waves independently.
// sout aliases xpre (read-before-write at same address by same thread).
// ---------------------------------------------------------------------------
__global__ __launch_bounds__(256, 1) void scan_rnn(
    const u16* __restrict__ Wh, const u16* __restrict__ xpre,
    const u16* __restrict__ zs, u16* __restrict__ sout,
    u16* __restrict__ hbuf, u32* __restrict__ done,
    void* __restrict__ dout, const int* __restrict__ dflag)
{
  const int fp32o = *dflag;
  const int wg   = blockIdx.x;
  const int tid  = threadIdx.x;
  const int lane = tid & 63;
  const int wave = tid >> 6;
  const int qq   = lane >> 4, ln = lane & 15;

  // persistent W_h fragments: A[m=lane&15][k=quad*8+j], rows wg*32 + i*16 + ln
  bf16x8 wfrag[2][10];
  #pragma unroll
  for (int i = 0; i < 2; ++i) {
    const u16* wrow = Wh + (long)(wg * RPW + i * 16 + ln) * D_ + wave * KS;
    #pragma unroll
    for (int c = 0; c < 10; ++c)
      wfrag[i][c] = *(const bf16x8*)(wrow + c * 32 + qq * 8);
  }

  __shared__ float red[8 * 272];   // [wave*2+tile][row(17-padded)*...]; +1 pad kills 16-way conflicts

  const int batch = tid >> 4;
  const int dl0   = (tid & 15) * 2;
  const int d0    = wg * RPW + dl0;
  const int tile  = dl0 >> 4;
  const int row0  = dl0 & 15;
  const int myf   = (lane < NW) ? lane : 0;      // flag this lane polls

  // preload step-0 inputs (h-independent)
  long pidx = (long)(0 * B_ + batch) * D_ + d0;
  u32 xp2 = *(const u32*)(xpre + pidx);
  u32 zs2 = *(const u32*)(zs + pidx);

  for (int t = 0; t < T_; ++t) {
    const u16* hc = hbuf + (t & 1) * (B_ * D_);
    u16*       hn = hbuf + ((t + 1) & 1) * (B_ * D_);

    // --- h fragments via L2-bypassing atomic loads; MFMA accumulate ---
    f32x4 a0 = (f32x4){0.f,0.f,0.f,0.f}, a1 = (f32x4){0.f,0.f,0.f,0.f};
    const u16* hrow = hc + (long)ln * D_ + wave * KS;   // B[n=batch=lane&15][k]
    #pragma unroll
    for (int c = 0; c < 10; ++c) {
      const u64* hq = (const u64*)(hrow + c * 32 + qq * 8);
      union { u64 q[2]; bf16x8 v; } hu;
      hu.q[0] = __hip_atomic_load(hq,     __ATOMIC_RELAXED, __HIP_MEMORY_SCOPE_AGENT);
      hu.q[1] = __hip_atomic_load(hq + 1, __ATOMIC_RELAXED, __HIP_MEMORY_SCOPE_AGENT);
      a0 = __builtin_amdgcn_mfma_f32_16x16x32_bf16(wfrag[0][c], hu.v, a0, 0, 0, 0);
      a1 = __builtin_amdgcn_mfma_f32_16x16x32_bf16(wfrag[1][c], hu.v, a1, 0, 0, 0);
    }
    #pragma unroll
    for (int r = 0; r < 4; ++r) {
      red[(wave * 2 + 0) * 272 + (qq * 4 + r) * 17 + ln] = a0[r];
      red[(wave * 2 + 1) * 272 + (qq * 4 + r) * 17 + ln] = a1[r];
    }
    __syncthreads();

    float s0 = red[(0 + tile) * 272 + row0 * 17 + batch]
             + red[(2 + tile) * 272 + row0 * 17 + batch]
             + red[(4 + tile) * 272 + row0 * 17 + batch]
             + red[(6 + tile) * 272 + row0 * 17 + batch];
    float s1 = red[(0 + tile) * 272 + (row0 + 1) * 17 + batch]
             + red[(2 + tile) * 272 + (row0 + 1) * 17 + batch]
             + red[(4 + tile) * 272 + (row0 + 1) * 17 + batch]
             + red[(6 + tile) * 272 + (row0 + 1) * 17 + batch];

    float h0 = tanh_(bf2f((u16)(xp2 & 0xffff)) + s0);
    float h1 = tanh_(bf2f((u16)(xp2 >> 16)) + s1);
    float o0 = h0 * bf2f((u16)(zs2 & 0xffff));   // zs already silu'd
    float o1 = h1 * bf2f((u16)(zs2 >> 16));

    *(u32*)(sout + pidx) = (u32)f2bf(o0) | ((u32)f2bf(o1) << 16);
    u32 hpack = (u32)f2bf(h0) | ((u32)f2bf(h1) << 16);
    __hip_atomic_store((u32*)(hn + batch * D_ + d0), hpack,
                       __ATOMIC_RELAXED, __HIP_MEMORY_SCOPE_AGENT);

    if (t == T_ - 1) {                           // h_final, dtype-branched
      if (fp32o) {
        float* hf32 = (float*)dout + (long)B_ * T_ * D_;
        hf32[batch * D_ + d0]     = h0;
        hf32[batch * D_ + d0 + 1] = h1;
      } else {
        u16* hb = (u16*)dout + (long)B_ * T_ * D_;
        *(u32*)(hb + batch * D_ + d0) = hpack;
      }
      break;                                     // uniform exit
    }

    // prefetch next step's inputs so HBM latency hides under the poll
    pidx = (long)((t + 1) * B_ + batch) * D_ + d0;
    u32 xp2n = *(const u32*)(xpre + pidx);
    u32 zs2n = *(const u32*)(zs + pidx);

    __syncthreads();          // drains vmcnt(0): h atomic stores are at LIC
    if (tid == 0)
      __hip_atomic_store(&done[(long)t * 64 + wg], 1u,
                         __ATOMIC_RELAXED, __HIP_MEMORY_SCOPE_AGENT);

    // every wave polls all 40 per-WG flags; waves release independently
    const u32* drow = done + (long)t * 64;
    for (;;) {
      u32 v = __hip_atomic_load(&drow[myf], __ATOMIC_RELAXED, __HIP_MEMORY_SCOPE_AGENT);
      if (__all(v != 0)) break;
    }

    xp2 = xp2n; zs2 = zs2n;
  }
}

// ---------------------------------------------------------------------------
extern "C" void kernel_launch(void* const* d_in, const int* in_sizes, int n_in,
                              void* d_out, int out_size, void* d_ws, size_t ws_size,
                              hipStream_t stream) {
  const void* x     = d_in[0];   // (16,2048,1280)
  const void* W_in  = d_in[1];   // (2560,1280)
  const void* W_out = d_in[2];   // (1280,1280)
  const void* W_x   = d_in[3];   // (1280,1280)
  const void* W_h   = d_in[4];   // (1280,1280)
  const void* bias  = d_in[5];   // (1280,)

  const size_t SZ = (size_t)32768 * D_ * sizeof(u16);  // 83,886,080 B
  char* ws = (char*)d_ws;
  u16* bufA  = (u16*)(ws);                        // x_bf16 -> xpre -> sout (in place)
  u16* bufB  = (u16*)(ws + SZ);                   // x_proj
  u16* wi    = (u16*)(ws + 2 * SZ);               // W_in  bf16 (6,553,600 B)
  u16* wo    = (u16*)(ws + 2 * SZ +  6553600);    // W_out bf16 (3,276,800 B)
  u16* wx    = (u16*)(ws + 2 * SZ +  9830400);    // W_x   bf16
  u16* wh    = (u16*)(ws + 2 * SZ + 13107200);    // W_h   bf16
  u16* bb_   = (u16*)(ws + 2 * SZ + 16384000);    // bias  bf16 (2,560 B)
  u16* hbuf  = (u16*)(ws + 2 * SZ + 16386560);    // 2 x (16 x 1280) bf16 ring (81,920 B)
  u32* done  = (u32*)(ws + 2 * SZ + 16386560 + 81920);           // T x 64 u32 (524,288 B)
  int* dflag = (int*)(ws + 2 * SZ + 16386560 + 81920 + 524288);
  u16* zsil  = (u16*)d_out;                       // silu(z) parks in d_out; dead
                                                  // before gemm<2> overwrites it

  hipMemsetAsync(hbuf, 0, 81920 + 524288, stream);

  detect_k<<<1, 256, 0, stream>>>((const u16*)x, dflag);
  cvt_k<<<20480, 256, 0, stream>>>(x,     bufA, 41943040L, dflag);
  cvt_k<<< 1600, 256, 0, stream>>>(W_in,  wi,    3276800L, dflag);
  cvt_k<<<  800, 256, 0, stream>>>(W_out, wo,    1638400L, dflag);
  cvt_k<<<  800, 256, 0, stream>>>(W_x,   wx,    1638400L, dflag);
  cvt_k<<<  800, 256, 0, stream>>>(W_h,   wh,    1638400L, dflag);
  cvt_k<<<    1, 256, 0, stream>>>(bias,  bb_,      1280L, dflag);

  gemm_bt<0><<<dim3(20, 256), 256, 0, stream>>>(bufA, wi, bufB, zsil, nullptr, nullptr, dflag);
  gemm_bt<1><<<dim3(10, 256), 256, 0, stream>>>(bufB, wx, bufA, nullptr, bb_, nullptr, dflag);
  scan_rnn<<<NW, 256, 0, stream>>>(wh, bufA, zsil, bufA, hbuf, done, d_out, dflag);
  gemm_bt<2><<<dim3(10, 256), 256, 0, stream>>>(bufA, wo, nullptr, nullptr, nullptr, d_out, dflag);
}